// Round 12
// baseline (192.934 us; speedup 1.0000x reference)
//
#include <hip/hip_runtime.h>
#include <stdint.h>

// Problem constants (fixed by reference)
#define NB 32    // batch
#define NC 64    // input channels
#define NH 64
#define NW 64
#define NO 512   // output channels
// xh padded layout (UNSWIZZLED): [NB][66 hp][66 wp][64 c], borders zero

typedef __bf16 bf16x8 __attribute__((ext_vector_type(8)));
typedef short  s16x8  __attribute__((ext_vector_type(8)));
typedef float  f32x4  __attribute__((ext_vector_type(4)));

__device__ __forceinline__ uint16_t f2bf(float f) {
  uint32_t u = __builtin_bit_cast(uint32_t, f);
  u += 0x7fffu + ((u >> 16) & 1u);   // round-to-nearest-even
  return (uint16_t)(u >> 16);
}

// async global->LDS, 16B per lane. LDS dest = wave-uniform base + lane*16.
__device__ __forceinline__ void gld16(const uint16_t* g, uint16_t* l) {
  __builtin_amdgcn_global_load_lds(
      (const __attribute__((address_space(1))) void*)(g),
      (__attribute__((address_space(3))) void*)(l), 16, 0, 0);
}

// ---------------- kernel 1: fused prep (build_w + nhwc transpose) --------
// bid < NO: W_eff[o][c][p] = sum_s coef[o,s]*dict[idx[o,s]][c][p] ->
//   Wl[((p*NO + o)*8 + ((c>>3) ^ (o&7)))*8 + (c&7)]   (A stays pre-swizzled
//   for conflict-free LDS; B/xh is now UNswizzled.)
// bid >= NO: x NCHW fp32 -> xh[b][hp][wp][c] bf16, hp/wp-padded (66x66).
__global__ void k_prep(const float* __restrict__ dict,
                       const float* __restrict__ coef,
                       const int*   __restrict__ idx,
                       const float* __restrict__ x,
                       uint16_t*    __restrict__ Wl,
                       uint16_t*    __restrict__ xh) {
  const int bid = blockIdx.x;
  const int t = threadIdx.x;            // 256
  if (bid < NO) {                       // ---- build_w for o = bid ----
    __shared__ float tmp[576];
    const int o = bid;
#pragma unroll
    for (int j = 0; j < 3; ++j) {
      const int id = t + j * 256;
      if (id < 576) {
        float v = 0.f;
#pragma unroll
        for (int s = 0; s < 4; ++s)
          v += coef[o * 4 + s] * dict[idx[o * 4 + s] * 576 + id];
        tmp[id] = v;
      }
    }
    __syncthreads();
#pragma unroll
    for (int j = 0; j < 3; ++j) {
      const int id = t + j * 256;
      if (id < 576) {
        const int c = id & 63, p = id >> 6;
        const int sl = ((p * NO + o) * 8 + ((c >> 3) ^ (o & 7))) * 8 + (c & 7);
        Wl[sl] = f2bf(tmp[c * 9 + p]);
      }
    }
    return;
  }
  // ---- nhwc for bh = bid - NO ----
  const int bh = bid - NO;              // b*66 + hp
  const int b = bh / 66, hp = bh % 66;
  uint16_t* row = xh + (size_t)(b * 66 + hp) * 4224;   // 66*64 elems
  int4* r4 = reinterpret_cast<int4*>(row);             // 528 int4
  if (hp == 0 || hp == 65) {            // zero h-pad rows
    for (int j = t; j < 528; j += 256) r4[j] = int4{0, 0, 0, 0};
    return;
  }
  __shared__ float tile[64][65];
  const int h = hp - 1;
  const int w = t & 63;
#pragma unroll
  for (int c = (t >> 6); c < 64; c += 4)
    tile[c][w] = x[((size_t)(b * NC + c) * NH + h) * NW + w];
  __syncthreads();
  if (t < 16)                           // zero w-pad cols wp=0 and wp=65
    r4[(t >> 3) * 520 + (t & 7)] = int4{0, 0, 0, 0};
#pragma unroll
  for (int i = 0; i < 2; ++i) {
    const int s = t + i * 256;          // 512 slots: w2 (0..63), cb (0..7)
    const int w2 = s >> 3, cb = s & 7;
    const int wp = w2 + 1;              // padded col
    uint32_t d[4];
#pragma unroll
    for (int j = 0; j < 4; ++j) {
      const uint32_t lo = f2bf(tile[cb * 8 + 2 * j][w2]);
      const uint32_t hi = f2bf(tile[cb * 8 + 2 * j + 1][w2]);
      d[j] = lo | (hi << 16);
    }
    r4[wp * 8 + cb] = int4{(int)d[0], (int)d[1], (int)d[2], (int)d[3]};
  }
}

// ---------------- kernel 2: high-occupancy conv, B-from-L2 ---------------
// 4096 blocks, 256 thr (4 waves). Block = 64 o x 256 pix (4 h-rows, one b);
// wave = 64 pix (1 h-row) x 64 o. acc[4][4] = 64 VGPR; total ~115 VGPR ->
// 4 waves/SIMD, 16 waves/CU (TLP hides ds/global latency -- the fix for
// 11 rounds of 2-waves/SIMD serialization).
// B fragments load DIRECTLY from L2-resident unswizzled xh (no xs, no
// staging barriers). LDS holds only A: 3-tap group x 64 o = 24 KB,
// restaged twice (5 barriers total in kernel).
__global__ __launch_bounds__(256, 4) void k_conv(
    const uint16_t* __restrict__ xh,   // [NB][66][66][64] bf16, unswizzled
    const uint16_t* __restrict__ Wl,   // [9][512][64] bf16, pre-swizzled
    const float*    __restrict__ bias,
    float*          __restrict__ out) {
  __shared__ __align__(16) uint16_t as[3 * 64 * 64];    // 24,576 B

  const int t = threadIdx.x;
  const int lane = t & 63;
  const int wid  = t >> 6;      // 0..3
  // XCD-chunked: o-tile fastest -> same pixels reused 8x on one XCD
  const int flat = blockIdx.x;                 // 4096 blocks
  const int s    = (flat & 7) * 512 + (flat >> 3);
  const int ot   = s & 7;                      // o-tile (8 x 64)
  const int pt   = s >> 3;                     // pixel tile: b*16 + h-quad
  const int O0 = ot * 64;
  const int b  = pt >> 4;
  const int h0 = (pt & 15) * 4;

  // ---- as staging: group g = taps p = dh*3 + g (dh 0..2), 64 o ----
  // 24 chunks of 1 KB; wave wid takes chunks wid*6 .. wid*6+5.
  auto stage_a = [&](int g) {
#pragma unroll
    for (int j = 0; j < 6; ++j) {
      const int c = wid * 6 + j;               // 0..23
      const int tap = c >> 3, k = c & 7;       // 8 chunks per tap
      const uint16_t* src =
          Wl + (size_t)(tap * 3 + g) * 32768 + (O0 + k * 8) * 64;
      gld16(src + lane * 8, as + tap * 4096 + k * 512);
    }
  };
  stage_a(0);

  const int wn  = wid;          // h-row within quad
  const int l15 = lane & 15;
  const int lg  = lane >> 4;    // k-group

  float bvv[4];
#pragma unroll
  for (int ob = 0; ob < 4; ++ob)
    bvv[ob] = bias[O0 + ob * 16 + l15];

  f32x4 acc[4][4] = {};

  __syncthreads();              // as(group0) resident

#pragma unroll
  for (int g = 0; g < 3; ++g) {
    const int dw = g - 1;
#pragma unroll
    for (int dh = 0; dh < 3; ++dh) {
      // B row base: xh[b][h0+wn+dh][dw+1 + pix][c]
      const uint16_t* xrow =
          xh + ((size_t)(b * 66) + h0 + wn + dh) * 4224 + (dw + 1) * 64;
#pragma unroll
      for (int q = 0; q < 2; ++q) {
        bf16x8 fb[4], fa[4];
#pragma unroll
        for (int nw = 0; nw < 4; ++nw)
          fb[nw] = __builtin_bit_cast(bf16x8,
              *reinterpret_cast<const s16x8*>(
                  xrow + (nw * 16 + l15) * 64 + q * 32 + lg * 8));
        const int sa = (q * 4 + lg) ^ (l15 & 7);
        const uint16_t* ab = as + dh * 4096 + l15 * 64 + sa * 8;
#pragma unroll
        for (int ob = 0; ob < 4; ++ob)
          fa[ob] = __builtin_bit_cast(bf16x8,
              *reinterpret_cast<const s16x8*>(ab + ob * 1024));
        __builtin_amdgcn_s_setprio(1);
#pragma unroll
        for (int pb = 0; pb < 4; ++pb)
#pragma unroll
          for (int ob = 0; ob < 4; ++ob)
            acc[pb][ob] = __builtin_amdgcn_mfma_f32_16x16x32_bf16(
                fb[pb], fa[ob], acc[pb][ob], 0, 0, 0);
        __builtin_amdgcn_s_setprio(0);
      }
    }
    if (g < 2) {
      __syncthreads();          // all waves done reading as(g)
      stage_a(g + 1);
      __syncthreads();          // as(g+1) resident
    }
  }

  // ---- epilogue: direct f32x4 nt stores (layout verified R7/R8) ----
  const int h = h0 + wn;
#pragma unroll
  for (int pb = 0; pb < 4; ++pb) {
#pragma unroll
    for (int ob = 0; ob < 4; ++ob) {
      const int o = O0 + ob * 16 + l15;
      f32x4 v = acc[pb][ob];
      const float bv = bvv[ob];
      v[0] += bv; v[1] += bv; v[2] += bv; v[3] += bv;
      float* dst = out + ((size_t)(b * NO + o) * NH + h) * NW +
                   pb * 16 + lg * 4;
      __builtin_nontemporal_store(v, reinterpret_cast<f32x4*>(dst));
    }
  }
}

extern "C" void kernel_launch(void* const* d_in, const int* in_sizes, int n_in,
                              void* d_out, int out_size, void* d_ws, size_t ws_size,
                              hipStream_t stream) {
  const float* x    = (const float*)d_in[0];
  const float* dict = (const float*)d_in[1];
  const float* coef = (const float*)d_in[2];
  const float* bias = (const float*)d_in[3];
  const int*   idx  = (const int*)d_in[4];
  float* out = (float*)d_out;

  // workspace: xh padded = 32*66*66*64*2 B = 17.84 MB at 0;
  //            Wl swizzled 576 KiB at +18 MiB
  uint16_t* xh = (uint16_t*)d_ws;
  uint16_t* Wl = (uint16_t*)((char*)d_ws + (18u << 20));

  hipLaunchKernelGGL(k_prep, dim3(NO + NB * 66), dim3(256), 0, stream,
                     dict, coef, idx, x, Wl, xh);
  hipLaunchKernelGGL(k_conv, dim3(4096), dim3(256), 0, stream,
                     xh, Wl, bias, out);
}

// Round 13
// 128.186 us; speedup vs baseline: 1.5051x; 1.5051x over previous
//
#include <hip/hip_runtime.h>
#include <stdint.h>

// Problem constants (fixed by reference)
#define NB 32    // batch
#define NC 64    // input channels
#define NH 64
#define NW 64
#define NO 512   // output channels
// xh layout: [NB][66 hp][64 w][64 c] bf16, hp 0 and 65 zero rows, swizzled:
//   16B chunk (c>>3) of col w stored at chunk slot ((c>>3) ^ (w&7)).
#define XROW 4096  // elems per xh row (64 w x 64 c)

typedef __bf16 bf16x8 __attribute__((ext_vector_type(8)));
typedef short  s16x8  __attribute__((ext_vector_type(8)));
typedef float  f32x4  __attribute__((ext_vector_type(4)));

__device__ __forceinline__ uint16_t f2bf(float f) {
  uint32_t u = __builtin_bit_cast(uint32_t, f);
  u += 0x7fffu + ((u >> 16) & 1u);   // round-to-nearest-even
  return (uint16_t)(u >> 16);
}

// async global->LDS, 16B per lane. LDS dest = wave-uniform base + lane*16.
__device__ __forceinline__ void gld16(const uint16_t* g, uint16_t* l) {
  __builtin_amdgcn_global_load_lds(
      (const __attribute__((address_space(1))) void*)(g),
      (__attribute__((address_space(3))) void*)(l), 16, 0, 0);
}

// ---------------- kernel 1: fused prep (build_w + nhwc transpose) --------
__global__ void k_prep(const float* __restrict__ dict,
                       const float* __restrict__ coef,
                       const int*   __restrict__ idx,
                       const float* __restrict__ x,
                       uint16_t*    __restrict__ Wl,
                       uint16_t*    __restrict__ xh) {
  const int bid = blockIdx.x;
  const int t = threadIdx.x;            // 256
  if (bid < NO) {                       // ---- build_w for o = bid ----
    __shared__ float tmp[576];
    const int o = bid;
#pragma unroll
    for (int j = 0; j < 3; ++j) {
      const int id = t + j * 256;
      if (id < 576) {
        float v = 0.f;
#pragma unroll
        for (int s = 0; s < 4; ++s)
          v += coef[o * 4 + s] * dict[idx[o * 4 + s] * 576 + id];
        tmp[id] = v;
      }
    }
    __syncthreads();
#pragma unroll
    for (int j = 0; j < 3; ++j) {
      const int id = t + j * 256;
      if (id < 576) {
        const int c = id & 63, p = id >> 6;
        const int sl = ((p * NO + o) * 8 + ((c >> 3) ^ (o & 7))) * 8 + (c & 7);
        Wl[sl] = f2bf(tmp[c * 9 + p]);
      }
    }
    return;
  }
  // ---- nhwc for bh = bid - NO ----
  const int bh = bid - NO;              // b*66 + hp
  const int b = bh / 66, hp = bh % 66;
  uint16_t* row = xh + (size_t)(b * 66 + hp) * XROW;
  int4* r4 = reinterpret_cast<int4*>(row);             // 512 int4
  if (hp == 0 || hp == 65) {            // zero h-pad rows
    r4[t]       = int4{0, 0, 0, 0};
    r4[t + 256] = int4{0, 0, 0, 0};
    return;
  }
  __shared__ float tile[64][65];
  const int h = hp - 1;
  const int w = t & 63;
#pragma unroll
  for (int c = (t >> 6); c < 64; c += 4)
    tile[c][w] = x[((size_t)(b * NC + c) * NH + h) * NW + w];
  __syncthreads();
#pragma unroll
  for (int i = 0; i < 2; ++i) {
    const int s = t + i * 256;          // 512 slots: w2 (0..63), cb (0..7)
    const int w2 = s >> 3, cb = s & 7;
    uint32_t d[4];
#pragma unroll
    for (int j = 0; j < 4; ++j) {
      const uint32_t lo = f2bf(tile[cb * 8 + 2 * j][w2]);
      const uint32_t hi = f2bf(tile[cb * 8 + 2 * j + 1][w2]);
      d[j] = lo | (hi << 16);
    }
    r4[w2 * 8 + (cb ^ (w2 & 7))] =
        int4{(int)d[0], (int)d[1], (int)d[2], (int)d[3]};
  }
}

// ---------------- kernel 2: 2-blocks/CU, 4-waves/SIMD conv ---------------
// 2048 blocks, 512 thr (8 waves). Block = 128 o x 256 pix (4 h-rows, one
// b). Wave = 64 o x 64 pix (1 h-row). acc[4][4] = 64 VGPR (~120 total,
// capped 128 by __launch_bounds__(512,4) -> 4 waves/SIMD with 2 blocks).
// LDS EXACTLY 80 KB -> 2 independent blocks/CU (the knob never yet turned):
//   xs = 6 xh rows (no w-pad) = 48 KB; boundary taps handled by clamp +
//        cndmask-zero on 2 edge lanes (dw=-1:w=0, dw=+1:w=63).
//   as = 2-tap group x 128 o = 32 KB, restaged 4x (9 barriers total;
//        partner block covers each drain).
__global__ __launch_bounds__(512, 4) void k_conv(
    const uint16_t* __restrict__ xh,   // [NB][66][64][64] bf16, pre-swizzled
    const uint16_t* __restrict__ Wl,   // [9][512][64] bf16, pre-swizzled
    const float*    __restrict__ bias,
    float*          __restrict__ out) {
  __shared__ __align__(16) uint16_t xs[6 * XROW];       // 49,152 B
  __shared__ __align__(16) uint16_t as[2 * 8192];       // 32,768 B

  const int t = threadIdx.x;
  const int lane = t & 63;
  const int wid  = t >> 6;      // 0..7
  // XCD-chunked: XCD j gets 4 b's (xh slice 2.1 MB + Wl L2-resident)
  const int flat = blockIdx.x;                 // 2048 blocks
  const int s    = (flat & 7) * 256 + (flat >> 3);
  const int ot   = s & 3;                      // o-tile (4 x 128)
  const int pt   = s >> 2;                     // pixel tile: b*16 + h-quad
  const int O0 = ot * 128;
  const int b  = pt >> 4;
  const int h0 = (pt & 15) * 4;

  // ---- stage xs: 6 rows (hp = h0 .. h0+5), 48 x 1KB chunks ----
  {
    const uint16_t* src = xh + (size_t)(b * 66 + h0) * XROW;
#pragma unroll
    for (int j = 0; j < 6; ++j) {
      const int ch = wid * 6 + j;              // 0..47
      gld16(src + ch * 512 + lane * 8, xs + ch * 512);
    }
  }
  // ---- as staging: group g = taps {2g, 2g+1} (g=4: tap 8 only) ----
  auto stage_grp = [&](int g) {
#pragma unroll
    for (int j = 0; j < 4; ++j) {
      const int ch = wid * 4 + j;              // 0..31
      const int tp = ch >> 4, k = ch & 15;     // 16 chunks per tap
      int p = g * 2 + tp; if (p > 8) p = 8;    // clamp (slot1 unread at g=4)
      const uint16_t* src = Wl + (size_t)p * 32768 + (O0 + k * 8) * 64;
      gld16(src + lane * 8, as + tp * 8192 + k * 512);
    }
  };
  stage_grp(0);

  const int wm  = wid & 1;      // o sub-block (64 each)
  const int wr  = wid >> 1;     // h-row within quad 0..3
  const int l15 = lane & 15;
  const int lg  = lane >> 4;    // k-group

  s16x8 zraw = {0, 0, 0, 0, 0, 0, 0, 0};
  const bf16x8 ZV = __builtin_bit_cast(bf16x8, zraw);

  float bvv[4];
#pragma unroll
  for (int ob = 0; ob < 4; ++ob)
    bvv[ob] = bias[O0 + wm * 64 + ob * 16 + l15];

  f32x4 acc[4][4] = {};

  __syncthreads();              // xs + as(group0) resident

#pragma unroll
  for (int g = 0; g < 5; ++g) {
#pragma unroll
    for (int tp = 0; tp < 2; ++tp) {
      if (g == 4 && tp == 1) break;            // 9 taps total
      const int p = g * 2 + tp;
      const int dh = p / 3, dw = p % 3 - 1;
      const uint16_t* xrow = xs + (wr + dh) * XROW;
      const uint16_t* ab   = as + tp * 8192 + (wm * 64 + l15) * 64;
#pragma unroll
      for (int q = 0; q < 2; ++q) {
        bf16x8 fb[4], fa[4];
#pragma unroll
        for (int nw = 0; nw < 4; ++nw) {
          int wc = nw * 16 + l15 + dw;
          wc = wc < 0 ? 0 : (wc > 63 ? 63 : wc);   // folds per (dw,nw)
          const int sl = (q * 4 + lg) ^ (wc & 7);
          bf16x8 v = __builtin_bit_cast(bf16x8,
              *reinterpret_cast<const s16x8*>(xrow + wc * 64 + sl * 8));
          if (dw == -1 && nw == 0) v = (l15 == 0)  ? ZV : v;
          if (dw == 1  && nw == 3) v = (l15 == 15) ? ZV : v;
          fb[nw] = v;
        }
        const int sa = (q * 4 + lg) ^ (l15 & 7);
#pragma unroll
        for (int ob = 0; ob < 4; ++ob)
          fa[ob] = __builtin_bit_cast(bf16x8,
              *reinterpret_cast<const s16x8*>(ab + ob * 1024 + sa * 8));
        __builtin_amdgcn_s_setprio(1);
#pragma unroll
        for (int pb = 0; pb < 4; ++pb)
#pragma unroll
          for (int ob = 0; ob < 4; ++ob)
            acc[pb][ob] = __builtin_amdgcn_mfma_f32_16x16x32_bf16(
                fb[pb], fa[ob], acc[pb][ob], 0, 0, 0);
        __builtin_amdgcn_s_setprio(0);
      }
    }
    if (g < 4) {
      __syncthreads();          // all waves done reading as(g)
      stage_grp(g + 1);
      __syncthreads();          // as(g+1) resident
    }
  }

  // ---- epilogue: direct f32x4 nt stores (layout verified R7/R8) ----
  const int h = h0 + wr;
#pragma unroll
  for (int pb = 0; pb < 4; ++pb) {
#pragma unroll
    for (int ob = 0; ob < 4; ++ob) {
      const int o = O0 + wm * 64 + ob * 16 + l15;
      f32x4 v = acc[pb][ob];
      const float bv = bvv[ob];
      v[0] += bv; v[1] += bv; v[2] += bv; v[3] += bv;
      float* dst = out + ((size_t)(b * NO + o) * NH + h) * NW +
                   pb * 16 + lg * 4;
      __builtin_nontemporal_store(v, reinterpret_cast<f32x4*>(dst));
    }
  }
}

extern "C" void kernel_launch(void* const* d_in, const int* in_sizes, int n_in,
                              void* d_out, int out_size, void* d_ws, size_t ws_size,
                              hipStream_t stream) {
  const float* x    = (const float*)d_in[0];
  const float* dict = (const float*)d_in[1];
  const float* coef = (const float*)d_in[2];
  const float* bias = (const float*)d_in[3];
  const int*   idx  = (const int*)d_in[4];
  float* out = (float*)d_out;

  // workspace: xh = 32*66*4096*2 B = 16.5 MiB at 0; Wl 576 KiB at +18 MiB
  uint16_t* xh = (uint16_t*)d_ws;
  uint16_t* Wl = (uint16_t*)((char*)d_ws + (18u << 20));

  hipLaunchKernelGGL(k_prep, dim3(NO + NB * 66), dim3(256), 0, stream,
                     dict, coef, idx, x, Wl, xh);
  hipLaunchKernelGGL(k_conv, dim3(2048), dim3(512), 0, stream,
                     xh, Wl, bias, out);
}

// Round 14
// 109.252 us; speedup vs baseline: 1.7660x; 1.1733x over previous
//
#include <hip/hip_runtime.h>
#include <stdint.h>

// Problem constants (fixed by reference)
#define NB 32    // batch
#define NC 64    // input channels
#define NH 64
#define NW 64
#define NO 512   // output channels
#define HP 66    // h-padded rows (1 zero row top+bottom)
// xh layout: [NB][66 hp][64 w][64 c] bf16, hp 0/65 zero rows, swizzled:
//   16B chunk (c>>3) of col w stored at chunk slot ((c>>3) ^ (w&7)).

typedef __bf16 bf16x8 __attribute__((ext_vector_type(8)));
typedef short  s16x8  __attribute__((ext_vector_type(8)));
typedef float  f32x4  __attribute__((ext_vector_type(4)));

__device__ __forceinline__ uint16_t f2bf(float f) {
  uint32_t u = __builtin_bit_cast(uint32_t, f);
  u += 0x7fffu + ((u >> 16) & 1u);   // round-to-nearest-even
  return (uint16_t)(u >> 16);
}

// async global->LDS, 16B per lane. LDS dest = wave-uniform base + lane*16.
__device__ __forceinline__ void gld16(const uint16_t* g, uint16_t* l) {
  __builtin_amdgcn_global_load_lds(
      (const __attribute__((address_space(1))) void*)(g),
      (__attribute__((address_space(3))) void*)(l), 16, 0, 0);
}

// ---------------- kernel 1: fused prep (build_w + nhwc transpose) --------
__global__ void k_prep(const float* __restrict__ dict,
                       const float* __restrict__ coef,
                       const int*   __restrict__ idx,
                       const float* __restrict__ x,
                       uint16_t*    __restrict__ Wl,
                       uint16_t*    __restrict__ xh) {
  const int bid = blockIdx.x;
  const int t = threadIdx.x;            // 256
  if (bid < NO) {                       // ---- build_w for o = bid ----
    __shared__ float tmp[576];
    const int o = bid;
#pragma unroll
    for (int j = 0; j < 3; ++j) {
      const int id = t + j * 256;
      if (id < 576) {
        float v = 0.f;
#pragma unroll
        for (int s = 0; s < 4; ++s)
          v += coef[o * 4 + s] * dict[idx[o * 4 + s] * 576 + id];
        tmp[id] = v;
      }
    }
    __syncthreads();
#pragma unroll
    for (int j = 0; j < 3; ++j) {
      const int id = t + j * 256;
      if (id < 576) {
        const int c = id & 63, p = id >> 6;
        const int sl = ((p * NO + o) * 8 + ((c >> 3) ^ (o & 7))) * 8 + (c & 7);
        Wl[sl] = f2bf(tmp[c * 9 + p]);
      }
    }
    return;
  }
  // ---- nhwc for bh = bid - NO ----
  const int bh = bid - NO;              // b*66 + hp
  const int b = bh / HP, hp = bh % HP;
  uint16_t* row = xh + (size_t)(b * HP + hp) * 4096;
  int4* r4 = reinterpret_cast<int4*>(row);             // 512 int4
  if (hp == 0 || hp == HP - 1) {        // zero h-pad rows
    r4[t]       = int4{0, 0, 0, 0};
    r4[t + 256] = int4{0, 0, 0, 0};
    return;
  }
  __shared__ float tile[64][65];
  const int h = hp - 1;
  const int w = t & 63;
#pragma unroll
  for (int c = (t >> 6); c < 64; c += 4)
    tile[c][w] = x[((size_t)(b * NC + c) * NH + h) * NW + w];
  __syncthreads();
#pragma unroll
  for (int i = 0; i < 2; ++i) {
    const int s = t + i * 256;          // 512 slots: w2 (0..63), cb (0..7)
    const int w2 = s >> 3, cb = s & 7;
    uint32_t d[4];
#pragma unroll
    for (int j = 0; j < 4; ++j) {
      const uint32_t lo = f2bf(tile[cb * 8 + 2 * j][w2]);
      const uint32_t hi = f2bf(tile[cb * 8 + 2 * j + 1][w2]);
      d[j] = lo | (hi << 16);
    }
    r4[w2 * 8 + (cb ^ (w2 & 7))] =
        int4{(int)d[0], (int)d[1], (int)d[2], (int)d[3]};
  }
}

// ---------------- kernel 2: persistent barrier-free conv -----------------
// 256 blocks (1/CU), 512 thr (8 waves). Block owns one (b, h-octet):
// xs (10 halo'd rows, 84.5 KB) staged ONCE; loop 8 o-tiles of 64.
// Per o-tile: barrier-free 18-step compute (R8 core verbatim), then
// {barrier; issue next tile's 9 gld16; issue 16 nt stores; vmcnt(16)
// (waits ONLY the gld16s, in-order); barrier} -> stores of tile i drain
// under tile i+1's compute. Double acc bank (static 2x unroll) so the
// compiler never inserts a store-drain wait to re-zero acc VGPRs.
__global__ __launch_bounds__(512, 2) void k_conv(
    const uint16_t* __restrict__ xh,   // [NB][66][64][64] bf16, pre-swizzled
    const uint16_t* __restrict__ Wl,   // [9][512][64] bf16, pre-swizzled
    const float*    __restrict__ bias,
    float*          __restrict__ out) {
  __shared__ __align__(16) uint16_t xs[10 * 66 * 64];     // 84,480 B
  __shared__ __align__(16) uint16_t as[9 * 64 * 64];      // 73,728 B

  const int t = threadIdx.x;
  const int lane = t & 63;
  const int wid  = t >> 6;      // 0..7
  const int blk = blockIdx.x;                  // 256 blocks
  // XCD-chunked: XCD k gets 32 consecutive gy (4 b's, L2-resident slice)
  const int gy = (blk & 7) * 32 + (blk >> 3);
  const int b  = gy >> 3;
  const int h0 = (gy & 7) * 8;

  // ---- zero the w-halo slots (slot 0 and 65 of each of 10 rows) ----
  if (t < 160) {
    const int r = t >> 4, sl = (t >> 3) & 1, j = t & 7;
    reinterpret_cast<int4*>(xs)[r * 528 + sl * 520 + j] = int4{0, 0, 0, 0};
  }
  // ---- stage x interior ONCE: rows 0..7 -> wave wid; rows 8,9 split ----
  {
    const uint16_t* srow = xh + (size_t)(b * HP + h0 + wid) * 4096;
    uint16_t* drow = xs + wid * 4224 + 64;     // skip w-halo slot 0
#pragma unroll
    for (int k = 0; k < 8; ++k)
      gld16(srow + k * 512 + lane * 8, drow + k * 512);
    const int r2 = 8 + (wid >> 2);
    const int kb = (wid & 3) * 2;
    const uint16_t* srow2 = xh + (size_t)(b * HP + h0 + r2) * 4096;
    uint16_t* drow2 = xs + r2 * 4224 + 64;
    gld16(srow2 + kb * 512 + lane * 8, drow2 + kb * 512);
    gld16(srow2 + (kb + 1) * 512 + lane * 8, drow2 + (kb + 1) * 512);
  }
  // ---- stage all 9 taps of o-tile ot: 72 x 1 KB chunks, 9 per wave ----
  auto stage_a = [&](int ot) {
#pragma unroll
    for (int j = 0; j < 9; ++j) {
      const int c = wid * 9 + j;               // 0..71
      const int tap = c >> 3, k = c & 7;
      const uint16_t* src = Wl + (size_t)tap * 32768 + (ot * 64) * 64 + k * 512;
      gld16(src + lane * 8, as + tap * 4096 + k * 512);
    }
  };
  stage_a(0);

  const int wn  = wid;          // h-row within octet
  const int l15 = lane & 15;
  const int lg  = lane >> 4;    // k-group

  // preload ALL bias (no mid-loop global loads -> vmcnt count stays exact)
  float bvv[8][4];
#pragma unroll
  for (int ot = 0; ot < 8; ++ot)
#pragma unroll
    for (int ob = 0; ob < 4; ++ob)
      bvv[ot][ob] = bias[ot * 64 + ob * 16 + l15];

  f32x4 accA[4][4], accB[4][4];

  __syncthreads();              // xs + as(ot=0) resident, bias loaded

  const int h = h0 + wn;

#define ROUND(ACC, OT) do {                                                  \
    _Pragma("unroll")                                                        \
    for (int pb = 0; pb < 4; ++pb)                                           \
      _Pragma("unroll")                                                      \
      for (int ob = 0; ob < 4; ++ob)                                         \
        ACC[pb][ob] = (f32x4){0.f, 0.f, 0.f, 0.f};                           \
    _Pragma("unroll")                                                        \
    for (int g = 0; g < 3; ++g) {                                            \
      const int dw = g - 1;                                                  \
      _Pragma("unroll")                                                      \
      for (int q = 0; q < 2; ++q) {                                          \
        const int cbB = (q * 4 + lg) ^ ((l15 + dw) & 7);                     \
        const uint16_t* xb = xs + (l15 + dw + 1) * 64 + cbB * 8;             \
        const int cbA = (q * 4 + lg) ^ (l15 & 7);                            \
        const uint16_t* ab = as + l15 * 64 + cbA * 8;                        \
        _Pragma("unroll")                                                    \
        for (int dh = 0; dh < 3; ++dh) {                                     \
          const int tap = dh * 3 + g;                                        \
          bf16x8 braw[4], af[4];                                             \
          _Pragma("unroll")                                                  \
          for (int nw = 0; nw < 4; ++nw)                                     \
            braw[nw] = __builtin_bit_cast(bf16x8,                            \
                *reinterpret_cast<const s16x8*>(                             \
                    xb + (wn + dh) * 4224 + nw * 1024));                     \
          _Pragma("unroll")                                                  \
          for (int ob = 0; ob < 4; ++ob)                                     \
            af[ob] = __builtin_bit_cast(bf16x8,                              \
                *reinterpret_cast<const s16x8*>(                             \
                    ab + tap * 4096 + ob * 1024));                           \
          _Pragma("unroll")                                                  \
          for (int pb = 0; pb < 4; ++pb)                                     \
            _Pragma("unroll")                                                \
            for (int ob = 0; ob < 4; ++ob)                                   \
              ACC[pb][ob] = __builtin_amdgcn_mfma_f32_16x16x32_bf16(         \
                  braw[pb], af[ob], ACC[pb][ob], 0, 0, 0);                   \
        }                                                                    \
      }                                                                      \
    }                                                                        \
    /* tile boundary: readers done -> restage -> stores -> counted wait */   \
    asm volatile("s_waitcnt lgkmcnt(0)" ::: "memory");                       \
    __builtin_amdgcn_s_barrier();                                            \
    asm volatile("" ::: "memory");                                           \
    if ((OT) < 7) stage_a((OT) + 1);           /* 9 gld16 (oldest) */        \
    asm volatile("" ::: "memory");                                           \
    _Pragma("unroll")                                                        \
    for (int pb = 0; pb < 4; ++pb) {                                         \
      _Pragma("unroll")                                                      \
      for (int ob = 0; ob < 4; ++ob) {                                       \
        const int o = (OT) * 64 + ob * 16 + l15;                             \
        f32x4 v = ACC[pb][ob];                                               \
        const float bv = bvv[(OT)][ob];                                      \
        v[0] += bv; v[1] += bv; v[2] += bv; v[3] += bv;                      \
        float* dst = out + ((size_t)(b * NO + o) * NH + h) * NW +            \
                     pb * 16 + lg * 4;                                       \
        __builtin_nontemporal_store(v, reinterpret_cast<f32x4*>(dst));       \
      }                                                                      \
    }                                                                        \
    asm volatile("" ::: "memory");                                           \
    if ((OT) < 7) {                                                          \
      asm volatile("s_waitcnt vmcnt(16)" ::: "memory"); /* gld16s landed */  \
      __builtin_amdgcn_s_barrier();                                          \
    }                                                                        \
  } while (0)

#pragma unroll
  for (int o2 = 0; o2 < 4; ++o2) {
    ROUND(accA, o2 * 2);
    ROUND(accB, o2 * 2 + 1);
  }
#undef ROUND
}

extern "C" void kernel_launch(void* const* d_in, const int* in_sizes, int n_in,
                              void* d_out, int out_size, void* d_ws, size_t ws_size,
                              hipStream_t stream) {
  const float* x    = (const float*)d_in[0];
  const float* dict = (const float*)d_in[1];
  const float* coef = (const float*)d_in[2];
  const float* bias = (const float*)d_in[3];
  const int*   idx  = (const int*)d_in[4];
  float* out = (float*)d_out;

  // workspace: xh = 32*66*4096*2 B = 16.5 MiB at 0; Wl 576 KiB at +18 MiB
  uint16_t* xh = (uint16_t*)d_ws;
  uint16_t* Wl = (uint16_t*)((char*)d_ws + (18u << 20));

  hipLaunchKernelGGL(k_prep, dim3(NO + NB * HP), dim3(256), 0, stream,
                     dict, coef, idx, x, Wl, xh);
  hipLaunchKernelGGL(k_conv, dim3(256), dim3(512), 0, stream,
                     xh, Wl, bias, out);
}